// Round 5
// baseline (101.146 us; speedup 1.0000x reference)
//
#include <hip/hip_runtime.h>
#include <stdint.h>

#define NB 256       // batch
#define NK 512       // in_features
#define NO 128       // out_features
#define NC 2048      // NO*KD
#define OUTW 640     // NK + NO
#define MAGIC 0x5A17C0DEu

typedef __attribute__((ext_vector_type(8))) short bf16x8;   // 8 bf16 (4 VGPRs)
typedef __attribute__((ext_vector_type(4))) float f32x4;
typedef __attribute__((ext_vector_type(4))) unsigned int u32x4;
typedef __attribute__((ext_vector_type(2))) unsigned int u32x2;

// pack 2 f32 -> 2 bf16 (truncation) in ONE v_perm_b32
__device__ __forceinline__ unsigned int pk(float lo, float hi) {
  return __builtin_amdgcn_perm(__builtin_bit_cast(unsigned int, hi),
                               __builtin_bit_cast(unsigned int, lo), 0x07060302u);
}

// ---------------------------------------------------------------------------
// Fused kernel, 1280 blocks:
//   bid <  256 : GEMM tile (BM=32,BN=64,BK=128, single-buffered LDS),
//                mt[o][a][kd] = sum_k x[a][k]*T[k][o*16+kd]; release-flag; exit.
//   bid >= 256 : pair block p=bid-256 -> (o=p>>3, bq=p&7). p<256 also does
//                x-copy. Spins on the 8 producer flags of column-block o>>2,
//                acquire-fence, then the (round-4-verified) LDS pair phase.
// All 1280 blocks co-resident (LDS 24.7KB -> 6/CU cap, need 5/CU) -> no
// deadlock. Flags never reset: first call is ordered (flags != MAGIC);
// replays may race benignly (mt is bit-identical across calls).
// ---------------------------------------------------------------------------
__global__ __launch_bounds__(256, 4) void k_fused(const float* __restrict__ x,
                                                  const float* __restrict__ T,
                                                  float* __restrict__ out,
                                                  float* __restrict__ mt,
                                                  unsigned int* __restrict__ flag) {
  __shared__ alignas(16) unsigned char smem[24704];
  const int tid = threadIdx.x;
  const int bid = blockIdx.x;

  if (bid < 256) {
    // =================== GEMM producer ===================
    unsigned short* lds = (unsigned short*)smem;   // As[32*128] @0, Bs[64*128] @4096
    const int bn = (bid & 31) * 64;                // col base (c)
    const int bm = (bid >> 5) * 32;                // row base (a)
    const int lane = tid & 63, wid = tid >> 6;
    const int wr = wid >> 1, wc = wid & 1;         // wave -> 16 rows x 32 cols

    int arow[2], akg[2], bkb[2], bcb[2];
#pragma unroll
    for (int s = 0; s < 2; ++s) { int idx = tid + s * 256; arow[s] = idx >> 4; akg[s] = idx & 15; }
#pragma unroll
    for (int s = 0; s < 2; ++s) { int idx = tid + s * 256; bkb[s] = idx >> 4; bcb[s] = idx & 15; }

    f32x4 raf[2][2], rbf[2][4];
    auto loadG = [&](int t) {
#pragma unroll
      for (int s = 0; s < 2; ++s) {
        const float* p = x + (size_t)(bm + arow[s]) * NK + t * 128 + akg[s] * 8;
        raf[s][0] = *(const f32x4*)p;
        raf[s][1] = *(const f32x4*)(p + 4);
      }
#pragma unroll
      for (int s = 0; s < 2; ++s)
#pragma unroll
        for (int j = 0; j < 4; ++j)
          rbf[s][j] = *(const f32x4*)(T + (size_t)(t * 128 + bkb[s] * 4 + j) * NC + bn + bcb[s] * 4);
    };
    auto writeS = [&]() {
#pragma unroll
      for (int s = 0; s < 2; ++s) {                // A: k-contiguous pack, b128
        u32x4 w;
        w[0] = pk(raf[s][0][0], raf[s][0][1]);
        w[1] = pk(raf[s][0][2], raf[s][0][3]);
        w[2] = pk(raf[s][1][0], raf[s][1][1]);
        w[3] = pk(raf[s][1][2], raf[s][1][3]);
        *(u32x4*)(&lds[arow[s] * 128 + ((akg[s] ^ (arow[s] & 7)) << 3)]) = w;
      }
#pragma unroll
      for (int s = 0; s < 2; ++s) {                // B: in-reg transpose, b64
        const int kb = bkb[s], kg = kb >> 1, k0l = (kb & 1) * 4;
#pragma unroll
        for (int c = 0; c < 4; ++c) {
          u32x2 w;
          w[0] = pk(rbf[s][0][c], rbf[s][1][c]);
          w[1] = pk(rbf[s][2][c], rbf[s][3][c]);
          int bc = bcb[s] * 4 + c;
          *(u32x2*)(&lds[4096 + bc * 128 + ((kg ^ (bc & 7)) << 3) + k0l]) = w;
        }
      }
    };

    f32x4 acc[2] = {};
    const int rowA  = wr * 16 + (lane & 15);
    const int colB0 = wc * 32 + (lane & 15);

    loadG(0); writeS(); __syncthreads();
#pragma unroll
    for (int t = 0; t < 4; ++t) {
      if (t < 3) loadG(t + 1);                     // next-chunk loads under MFMA
#pragma unroll
      for (int ks = 0; ks < 4; ++ks) {
        int kg = ks * 4 + (lane >> 4);             // k-group of 8
        bf16x8 af = *(const bf16x8*)(&lds[rowA * 128 + ((kg ^ (rowA & 7)) << 3)]);
#pragma unroll
        for (int ct = 0; ct < 2; ++ct) {
          int col = colB0 + ct * 16;
          bf16x8 bv = *(const bf16x8*)(&lds[4096 + col * 128 + ((kg ^ (col & 7)) << 3)]);
          acc[ct] = __builtin_amdgcn_mfma_f32_16x16x32_bf16(af, bv, acc[ct], 0, 0, 0);
        }
      }
      if (t < 3) { __syncthreads(); writeS(); __syncthreads(); }
    }

    // C/D layout (verified): col = lane&15, row = (lane>>4)*4 + j
#pragma unroll
    for (int ct = 0; ct < 2; ++ct) {
      int colg = bn + wc * 32 + ct * 16 + (lane & 15);
      int o = colg >> 4, kd = colg & 15;
      int rbase = bm + wr * 16 + (lane >> 4) * 4;
#pragma unroll
      for (int j = 0; j < 4; ++j)
        mt[(size_t)o * 4096 + (size_t)(rbase + j) * 16 + kd] = acc[ct][j];
    }
    __syncthreads();                               // all stores drained (vmcnt 0)
    if (tid == 0)
      __hip_atomic_store(&flag[bid], MAGIC, __ATOMIC_RELEASE, __HIP_MEMORY_SCOPE_AGENT);
    return;
  }

  // =================== pair consumer ===================
  const int p = bid - 256;
  const int o = p >> 3, bq = p & 7;

  if (p < 256 && tid < 128) {                      // x-copy (independent work)
    int idx = p * 128 + tid;
    int row = idx >> 7, c4 = (idx & 127) * 4;
    *(f32x4*)(out + (size_t)row * OUTW + c4) = *(const f32x4*)(x + (size_t)row * NK + c4);
  }

  if (tid < 8) {                                   // wait for the 8 producers of o>>2
    const unsigned int* f = &flag[tid * 32 + (o >> 2)];
    while (__hip_atomic_load(f, __ATOMIC_RELAXED, __HIP_MEMORY_SCOPE_AGENT) != MAGIC)
      __builtin_amdgcn_s_sleep(2);
  }
  __syncthreads();
  __threadfence();                                 // acquire: invalidate L1/L2

  float* S = (float*)smem;                         // a-row r at S[r*20]
  float (*red)[33] = (float(*)[33])(smem + 20480);
  const float* __restrict__ mo = mt + (size_t)o * 4096;

#pragma unroll
  for (int s = 0; s < 4; ++s) {                    // stage 16KB o-slice
    int idx = tid + s * 256;
    f32x4 v = ((const f32x4*)mo)[idx];
    *(f32x4*)(&S[(idx >> 2) * 20 + (idx & 3) * 4]) = v;
  }
  __syncthreads();

  const int bg = tid & 7, aq = tid >> 3;
  const int wv = tid >> 6, aqr = aq & 7;
  const int r0 = bq * 32 + bg * 4;                 // this thread's 4 b-rows

  f32x4 br[4][4];
#pragma unroll
  for (int r = 0; r < 4; ++r)
#pragma unroll
    for (int i = 0; i < 4; ++i)
      br[r][i] = *(const f32x4*)(&S[(r0 + r) * 20 + i * 4]);

  float acc[4] = {0.f, 0.f, 0.f, 0.f};
#pragma unroll 2
  for (int it = 0; it < 8; ++it) {
    const int a = it * 32 + wv * 8 + aqr;          // bank-disjoint lane groups
    f32x4 ra[4];
#pragma unroll
    for (int i = 0; i < 4; ++i)
      ra[i] = *(const f32x4*)(&S[a * 20 + i * 4]);
#pragma unroll
    for (int r = 0; r < 4; ++r) {
      float n = 0.f;
#pragma unroll
      for (int i = 0; i < 4; ++i)
#pragma unroll
        for (int j = 0; j < 4; ++j)
          n += fabsf(ra[i][j] - br[r][i][j]);      // sub + add|abs|
      acc[r] += __expf(-n);                        // 0 for a!=b (underflow), 1 self
    }
  }
#pragma unroll
  for (int r = 0; r < 4; ++r) red[aq][bg * 4 + r] = acc[r];
  __syncthreads();
  if (tid < 32) {
    float s = 0.f;
#pragma unroll
    for (int q = 0; q < 32; ++q) s += red[q][tid];
    out[(size_t)(bq * 32 + tid) * OUTW + NK + o] = s;
  }
}

// ---------------------------------------------------------------------------
extern "C" void kernel_launch(void* const* d_in, const int* in_sizes, int n_in,
                              void* d_out, int out_size, void* d_ws, size_t ws_size,
                              hipStream_t stream) {
  const float* x = (const float*)d_in[0];
  const float* T = (const float*)d_in[1];
  float* out = (float*)d_out;
  char* ws = (char*)d_ws;
  float* mt = (float*)ws;                                   // 2 MB
  unsigned int* flag = (unsigned int*)(ws + (2u << 20));    // 256 flags

  k_fused<<<1280, 256, 0, stream>>>(x, T, out, mt, flag);
}

// Round 6
// 20.625 us; speedup vs baseline: 4.9040x; 4.9040x over previous
//
#include <hip/hip_runtime.h>
#include <hip/hip_fp16.h>
#include <stdint.h>

#define NB 256       // batch
#define NK 512       // in_features
#define NO 128       // out_features
#define NC 2048      // NO*KD
#define OUTW 640     // NK + NO

typedef __attribute__((ext_vector_type(8))) short bf16x8;   // 8 bf16 (4 VGPRs)
typedef __attribute__((ext_vector_type(4))) float f32x4;
typedef __attribute__((ext_vector_type(4))) unsigned int u32x4;
typedef __attribute__((ext_vector_type(2))) unsigned int u32x2;

// pack 2 f32 -> 2 bf16 (truncation) in ONE v_perm_b32
__device__ __forceinline__ unsigned int pk(float lo, float hi) {
  return __builtin_amdgcn_perm(__builtin_bit_cast(unsigned int, hi),
                               __builtin_bit_cast(unsigned int, lo), 0x07060302u);
}

// ---------------------------------------------------------------------------
// Kernel 1 (prep+gemm fused): mt[o][a][kd] = (half) sum_k x[a][k]*T[k][o*16+kd]
// BM=32 (a), BN=64 (c), BK=128, K=512 in 4 chunks; grid (32 N) x (8 M).
// Double-buffered LDS, XOR-swizzled (rounds 1-5 verified). fp16 epilogue:
// exactness of the pair self-term doesn't depend on cvt rounding (same
// stored value read twice -> diff exactly 0), and off-diagonal exp terms
// are < 2^-24 with probability ~1e-20. x-copy folded in.
// ---------------------------------------------------------------------------
__global__ __launch_bounds__(256) void k_gemm(const float* __restrict__ x,
                                              const float* __restrict__ T,
                                              float* __restrict__ out,
                                              __half* __restrict__ mt) {
  __shared__ unsigned short lds[2][12288];  // As[32*128] @0, Bs[64*128] @4096 (elems)
  const int tid = threadIdx.x;
  const int bn = blockIdx.x * 64;           // col base (c)
  const int bm = blockIdx.y * 32;           // row base (a)
  const int lane = tid & 63, wid = tid >> 6;
  const int wr = wid >> 1, wc = wid & 1;    // wave -> 16 rows x 32 cols

  // x-copy to out (independent work): 256 blocks * 128 f32x4
  {
    const int bid = blockIdx.y * 32 + blockIdx.x;
    if (tid < 128) {
      int idx = bid * 128 + tid;
      int row = idx >> 7, c4 = (idx & 127) * 4;
      *(f32x4*)(out + (size_t)row * OUTW + c4) = *(const f32x4*)(x + (size_t)row * NK + c4);
    }
  }

  // A staging: 32 rows x 16 kgroups(8) = 512 slots, 2/thread
  int arow[2], akg[2], bkb[2], bcb[2];
#pragma unroll
  for (int s = 0; s < 2; ++s) { int idx = tid + s * 256; arow[s] = idx >> 4; akg[s] = idx & 15; }
  // B staging: 32 kblk(4) x 16 cblk(4) = 512 micro-tiles, 2/thread
#pragma unroll
  for (int s = 0; s < 2; ++s) { int idx = tid + s * 256; bkb[s] = idx >> 4; bcb[s] = idx & 15; }

  f32x4 raf[2][2], rbf[2][4];
  auto loadG = [&](int t) {
#pragma unroll
    for (int s = 0; s < 2; ++s) {
      const float* p = x + (size_t)(bm + arow[s]) * NK + t * 128 + akg[s] * 8;
      raf[s][0] = *(const f32x4*)p;
      raf[s][1] = *(const f32x4*)(p + 4);
    }
#pragma unroll
    for (int s = 0; s < 2; ++s)
#pragma unroll
      for (int j = 0; j < 4; ++j)
        rbf[s][j] = *(const f32x4*)(T + (size_t)(t * 128 + bkb[s] * 4 + j) * NC + bn + bcb[s] * 4);
  };
  auto writeS = [&](int b) {
#pragma unroll
    for (int s = 0; s < 2; ++s) {           // A: k-contiguous pack, b128 write
      u32x4 w;
      w[0] = pk(raf[s][0][0], raf[s][0][1]);
      w[1] = pk(raf[s][0][2], raf[s][0][3]);
      w[2] = pk(raf[s][1][0], raf[s][1][1]);
      w[3] = pk(raf[s][1][2], raf[s][1][3]);
      *(u32x4*)(&lds[b][arow[s] * 128 + ((akg[s] ^ (arow[s] & 7)) << 3)]) = w;
    }
#pragma unroll
    for (int s = 0; s < 2; ++s) {           // B: in-reg transpose, b64 writes
      const int kb = bkb[s], kg = kb >> 1, k0l = (kb & 1) * 4;
#pragma unroll
      for (int c = 0; c < 4; ++c) {
        u32x2 w;
        w[0] = pk(rbf[s][0][c], rbf[s][1][c]);
        w[1] = pk(rbf[s][2][c], rbf[s][3][c]);
        int bc = bcb[s] * 4 + c;
        *(u32x2*)(&lds[b][4096 + bc * 128 + ((kg ^ (bc & 7)) << 3) + k0l]) = w;
      }
    }
  };

  f32x4 acc[2] = {};
  const int rowA  = wr * 16 + (lane & 15);
  const int colB0 = wc * 32 + (lane & 15);

  loadG(0); writeS(0); __syncthreads();
#pragma unroll
  for (int t = 0; t < 4; ++t) {
    if (t < 3) loadG(t + 1);                // issue next-chunk loads early
    const int b = t & 1;
#pragma unroll
    for (int ks = 0; ks < 4; ++ks) {
      int kg = ks * 4 + (lane >> 4);        // k-group of 8
      bf16x8 af = *(const bf16x8*)(&lds[b][rowA * 128 + ((kg ^ (rowA & 7)) << 3)]);
#pragma unroll
      for (int ct = 0; ct < 2; ++ct) {
        int col = colB0 + ct * 16;
        bf16x8 bv = *(const bf16x8*)(&lds[b][4096 + col * 128 + ((kg ^ (col & 7)) << 3)]);
        acc[ct] = __builtin_amdgcn_mfma_f32_16x16x32_bf16(af, bv, acc[ct], 0, 0, 0);
      }
    }
    if (t < 3) writeS((t + 1) & 1);         // pack+write under MFMA/load shadow
    __syncthreads();
  }

  // C/D layout (verified): col = lane&15, row = (lane>>4)*4 + j; fp16 store
#pragma unroll
  for (int ct = 0; ct < 2; ++ct) {
    int colg = bn + wc * 32 + ct * 16 + (lane & 15);
    int o = colg >> 4, kd = colg & 15;
    int rbase = bm + wr * 16 + (lane >> 4) * 4;
#pragma unroll
    for (int j = 0; j < 4; ++j)
      mt[(size_t)o * 4096 + (size_t)(rbase + j) * 16 + kd] = __float2half(acc[ct][j]);
  }
}

// ---------------------------------------------------------------------------
// Kernel 2: o_b[b][o] = sum_a exp(-sum_kd |mt[o][a][kd] - mt[o][b][kd]|)
// grid 1024 = (o, b-eighth), 4 blocks/CU. 8 KB fp16 o-slice in LDS with a
// bank-set-rotating row swizzle: row r at byte r*32 ^ (((r>>2)&3)<<5)
// (bijective; br-group reads drop from 8-way to 2-way, a-broadcast <=2-way).
// Inner math in packed half2 (v_pk_sub/and/add): 23 VALU per 16 elems.
// ---------------------------------------------------------------------------
__global__ __launch_bounds__(256, 4) void k_pair(const __half* __restrict__ mt,
                                                 float* __restrict__ out) {
  __shared__ unsigned char S[8192];         // swizzled o-slice: 256 rows * 32B
  __shared__ float red[32][33];
  const int tid = threadIdx.x, bid = blockIdx.x;
  const int o = bid >> 3, bq = bid & 7;
  const __half* __restrict__ mo = mt + (size_t)o * 4096;

  // stage 8KB: 512 x 16B chunks, 2/thread (swizzle keeps writes <=2-way)
#pragma unroll
  for (int s = 0; s < 2; ++s) {
    int idx = tid + s * 256;
    int row = idx >> 1, h = idx & 1;
    u32x4 v = ((const u32x4*)mo)[idx];
    *(u32x4*)(&S[((row * 32) ^ (((row >> 2) & 3) << 5)) + h * 16]) = v;
  }
  __syncthreads();

  const int bg = tid & 7, aq = tid >> 3;    // aq 0..31
  const int wv = tid >> 6, aqr = aq & 7;
  const int r0 = bq * 32 + bg * 4;          // this thread's 4 b-rows

  __half2 br[4][8];
#pragma unroll
  for (int r = 0; r < 4; ++r) {
    const __half2* p = (const __half2*)&S[((r0 + r) * 32) ^ ((((r0 + r) >> 2) & 3) << 5)];
#pragma unroll
    for (int i = 0; i < 8; ++i) br[r][i] = p[i];
  }

  float acc[4] = {0.f, 0.f, 0.f, 0.f};
#pragma unroll 2
  for (int it = 0; it < 8; ++it) {
    const int a = it * 32 + wv * 8 + aqr;   // 8-lane groups broadcast
    const __half2* pa = (const __half2*)&S[(a * 32) ^ (((a >> 2) & 3) << 5)];
    __half2 ra[8];
#pragma unroll
    for (int i = 0; i < 8; ++i) ra[i] = pa[i];
#pragma unroll
    for (int r = 0; r < 4; ++r) {
      __half2 s2 = __habs2(__hsub2(ra[0], br[r][0]));
#pragma unroll
      for (int i = 1; i < 8; ++i)
        s2 = __hadd2(s2, __habs2(__hsub2(ra[i], br[r][i])));
      float n = __low2float(s2) + __high2float(s2);
      acc[r] += __expf(-n);                 // 0 for a!=b (underflow), 1 self
    }
  }
#pragma unroll
  for (int r = 0; r < 4; ++r) red[aq][bg * 4 + r] = acc[r];
  __syncthreads();
  if (tid < 32) {
    float s = 0.f;
#pragma unroll
    for (int q = 0; q < 32; ++q) s += red[q][tid];
    out[(size_t)(bq * 32 + tid) * OUTW + NK + o] = s;
  }
}

// ---------------------------------------------------------------------------
extern "C" void kernel_launch(void* const* d_in, const int* in_sizes, int n_in,
                              void* d_out, int out_size, void* d_ws, size_t ws_size,
                              hipStream_t stream) {
  const float* x = (const float*)d_in[0];
  const float* T = (const float*)d_in[1];
  float* out = (float*)d_out;
  __half* mt = (__half*)d_ws;               // 1 MB scratch

  k_gemm<<<dim3(32, 8), 256, 0, stream>>>(x, T, out, mt);
  k_pair<<<1024, 256, 0, stream>>>(mt, out);
}